// Round 5
// baseline (62.354 us; speedup 1.0000x reference)
//
#include <hip/hip_runtime.h>
#include <hip/hip_cooperative_groups.h>

namespace cg = cooperative_groups;

// EdgeSelectionRL: out[b,i,j] = sigmoid( sum_h relu(A[b,i,h] + Cc[b,j,h]) * w2[h] + b2 )
// A = xa·Wa^T + b1, Cc = xa·Wb^T.  B=8, C=256, F=128, H=256.
// R5: SINGLE cooperative kernel. Phase 1 (waves 0-3 per block) = R4's MFMA
// projection; grid.sync(); Phase 2 = R4's k2 pairwise (w2 held in registers).
// Model: ~16us fixed replay pedestal + ~3.5us/node + ~4.5us work -> one node saves ~3.5us.

typedef _Float16 h2 __attribute__((ext_vector_type(2)));
typedef _Float16 h8 __attribute__((ext_vector_type(8)));
typedef float    f4 __attribute__((ext_vector_type(4)));

constexpr int B  = 8;
constexpr int C  = 256;
constexpr int F  = 128;
constexpr int H  = 256;
constexpr int F2 = 2 * F;     // 256
constexpr int HOCT = H / 8;   // 32
constexpr int TI = 8;
constexpr int HS = 4;

#if __has_builtin(__builtin_amdgcn_fdot2)
__device__ __forceinline__ float fdot2(h2 a, h2 b, float c) {
    return __builtin_amdgcn_fdot2(a, b, c, false);
}
#else
__device__ __forceinline__ float fdot2(h2 a, h2 b, float c) {
    return c + (float)a.x * (float)b.x + (float)a.y * (float)b.y;
}
#endif

__device__ __forceinline__ h8 cvt8(float4 a, float4 b) {
    h8 r;
    r[0] = (_Float16)a.x; r[1] = (_Float16)a.y; r[2] = (_Float16)a.z; r[3] = (_Float16)a.w;
    r[4] = (_Float16)b.x; r[5] = (_Float16)b.y; r[6] = (_Float16)b.z; r[7] = (_Float16)b.w;
    return r;
}

__global__ __launch_bounds__(1024) void fused_kernel(
    const float* __restrict__ xa, const float* __restrict__ W1,
    const float* __restrict__ b1, const float* __restrict__ w2,
    const float* __restrict__ b2p, float* __restrict__ out,
    _Float16* __restrict__ Ah, _Float16* __restrict__ CP8)
{
    __shared__ float red[(HS - 1) * TI * C];   // 24 KB
    const int t   = threadIdx.x;
    const int blk = blockIdx.x;

    // ---------------- Phase 1: projection (waves 0..3 of each block) --------
    // Wave w (= blk*4 + wv, 0..1023): 2 m-tiles at w>>4 * 32, h-tile (w&15)*16.
    // Direct f32 global fragment loads, cvt in-register, 16 MFMA.
    // D layout (m89): lane l, reg r -> row m0+(l>>4)*4+r, col h0+(l&15).
    if (t < 256) {
        const int w  = blk * 4 + (t >> 6);      // 0..1023
        const int l  = t & 63;
        const int mg = w >> 4;                  // 0..63
        const int h0 = (w & 15) * 16;
        const int lm = l & 15;
        const int lk = (l >> 4) * 8;
        const int m0 = mg * 32;

        h8 af[2][4];
        const float* xp0 = xa + (size_t)(m0 + lm) * F + lk;
        const float* xp1 = xp0 + 16 * F;
        #pragma unroll
        for (int kk = 0; kk < 4; ++kk) {
            af[0][kk] = cvt8(*(const float4*)(xp0 + kk * 32),
                             *(const float4*)(xp0 + kk * 32 + 4));
            af[1][kk] = cvt8(*(const float4*)(xp1 + kk * 32),
                             *(const float4*)(xp1 + kk * 32 + 4));
        }

        const float* wp = W1 + (size_t)(h0 + lm) * F2 + lk;
        f4 accA0 = {0.f,0.f,0.f,0.f}, accA1 = {0.f,0.f,0.f,0.f};
        f4 accC0 = {0.f,0.f,0.f,0.f}, accC1 = {0.f,0.f,0.f,0.f};
        #pragma unroll
        for (int kk = 0; kk < 4; ++kk) {
            h8 ba = cvt8(*(const float4*)(wp + kk * 32),
                         *(const float4*)(wp + kk * 32 + 4));
            h8 bb = cvt8(*(const float4*)(wp + F + kk * 32),
                         *(const float4*)(wp + F + kk * 32 + 4));
            accA0 = __builtin_amdgcn_mfma_f32_16x16x32_f16(af[0][kk], ba, accA0, 0, 0, 0);
            accC0 = __builtin_amdgcn_mfma_f32_16x16x32_f16(af[0][kk], bb, accC0, 0, 0, 0);
            accA1 = __builtin_amdgcn_mfma_f32_16x16x32_f16(af[1][kk], ba, accA1, 0, 0, 0);
            accC1 = __builtin_amdgcn_mfma_f32_16x16x32_f16(af[1][kk], bb, accC1, 0, 0, 0);
        }

        const int h   = h0 + lm;
        const float bh = b1[h];
        #pragma unroll
        for (int mt = 0; mt < 2; ++mt) {
            const f4 aA = mt ? accA1 : accA0;
            const f4 aC = mt ? accC1 : accC0;
            const int mb = m0 + mt * 16 + (l >> 4) * 4;
            #pragma unroll
            for (int r = 0; r < 4; ++r) {
                const int m = mb + r;
                Ah[(size_t)m * H + h] = (_Float16)(aA[r] + bh);
                // h-octet-packed Cc: CP8[((b*HOCT+h/8)*C + i)*8 + (h&7)]
                CP8[(((size_t)((m >> 8) * HOCT + (h >> 3)) * C + (m & 255)) << 3) + (h & 7)]
                    = (_Float16)aC[r];
            }
        }
    }

    // ---------------- Phase 2 prelude: w2 slice -> registers ----------------
    const int j  = t & 255;
    const int hs = t >> 8;                     // wave-uniform
    h8 w2r[8];
    {
        const float4* wq = (const float4*)(w2 + hs * 64);
        #pragma unroll
        for (int o = 0; o < 8; ++o)
            w2r[o] = cvt8(wq[2 * o], wq[2 * o + 1]);
    }

    cg::this_grid().sync();

    // ---------------- Phase 2: pairwise relu-dot + sigmoid ------------------
    // Block = (b, 8 i-rows): 256 j x 4 h-splits. A octets same-addr per wave
    // (L1 broadcast); cc octets 16B/lane coalesced; w2 from registers.
    const int it = blk & 31;
    const int b  = blk >> 5;
    const int i0 = it * TI;

    float acc[TI];
    #pragma unroll
    for (int ii = 0; ii < TI; ++ii) acc[ii] = 0.f;

    const int g0 = hs * (HOCT / HS);           // 8 octets per split
    const _Float16* Ab = Ah + (size_t)(b * C + i0) * H;

    union U { h8 v; h2 p[4]; };
    #pragma unroll
    for (int g = 0; g < HOCT / HS; ++g) {
        const int hb = g0 + g;
        h8 cc = *(const h8*)(CP8 + (((size_t)(b * HOCT + hb) * C + j) << 3));
        U uw; uw.v = w2r[g];
        #pragma unroll
        for (int ii = 0; ii < TI; ++ii) {
            h8 av = *(const h8*)(Ab + ii * H + hb * 8);   // same addr per wave
            h8 s = av + cc;                                // v_pk_add_f16
            h8 z = {0, 0, 0, 0, 0, 0, 0, 0};
            s = __builtin_elementwise_max(s, z);           // v_pk_max_f16
            U us; us.v = s;
            float a0 = acc[ii];
            a0 = fdot2(us.p[0], uw.p[0], a0);              // v_dot2_f32_f16
            a0 = fdot2(us.p[1], uw.p[1], a0);
            a0 = fdot2(us.p[2], uw.p[2], a0);
            a0 = fdot2(us.p[3], uw.p[3], a0);
            acc[ii] = a0;
        }
    }

    if (hs > 0) {
        #pragma unroll
        for (int ii = 0; ii < TI; ++ii)
            red[((hs - 1) * TI + ii) * C + j] = acc[ii];
    }
    __syncthreads();
    if (hs == 0) {
        const float bb = b2p[0];
        #pragma unroll
        for (int ii = 0; ii < TI; ++ii) {
            float x = acc[ii]
                    + red[(0 * TI + ii) * C + j]
                    + red[(1 * TI + ii) * C + j]
                    + red[(2 * TI + ii) * C + j] + bb;
            out[(size_t)(b * C + i0 + ii) * C + j] = 1.f / (1.f + __expf(-x));
        }
    }
}

extern "C" void kernel_launch(void* const* d_in, const int* in_sizes, int n_in,
                              void* d_out, int out_size, void* d_ws, size_t ws_size,
                              hipStream_t stream) {
    const float* xa = (const float*)d_in[0];
    const float* W1 = (const float*)d_in[1];
    const float* b1 = (const float*)d_in[2];
    const float* w2 = (const float*)d_in[3];
    const float* b2 = (const float*)d_in[4];
    float* out = (float*)d_out;

    _Float16* Ah  = (_Float16*)d_ws;                  // 1 MB
    _Float16* CP8 = Ah + (size_t)B * C * H;           // 1 MB

    void* args[] = { (void*)&xa, (void*)&W1, (void*)&b1, (void*)&w2,
                     (void*)&b2, (void*)&out, (void*)&Ah, (void*)&CP8 };
    hipLaunchCooperativeKernel((void*)fused_kernel, dim3(256), dim3(1024),
                               args, 0, stream);
}

// Round 6
// 30.341 us; speedup vs baseline: 2.0551x; 2.0551x over previous
//
#include <hip/hip_runtime.h>

// EdgeSelectionRL: out[b,i,j] = sigmoid( sum_h relu(A[b,i,h] + Cc[b,j,h]) * w2[h] + b2 )
// A = xa·Wa^T + b1, Cc = xa·Wb^T.  B=8, C=256, F=128, H=256.
// R6: 2 nodes (coop grid.sync cost ~40us -> abandoned). k1 = R4 verbatim.
// k2 -> MFMA-matvec: S=relu(a+c) built as 16x16x32 A-frags (2 pk-VALU per 2h),
// dot vs w2-replicated B-frag on the idle MFMA pipe. No LDS, no cross-wave reduce.
// Model: 15.1us base + 2.1/node + work (k1 ~0.7, k2 ~2.2).

typedef _Float16 h2 __attribute__((ext_vector_type(2)));
typedef _Float16 h8 __attribute__((ext_vector_type(8)));
typedef float    f4 __attribute__((ext_vector_type(4)));

constexpr int B  = 8;
constexpr int C  = 256;
constexpr int F  = 128;
constexpr int H  = 256;
constexpr int F2 = 2 * F;     // 256
constexpr int HOCT = H / 8;   // 32

__device__ __forceinline__ h8 cvt8(float4 a, float4 b) {
    h8 r;
    r[0] = (_Float16)a.x; r[1] = (_Float16)a.y; r[2] = (_Float16)a.z; r[3] = (_Float16)a.w;
    r[4] = (_Float16)b.x; r[5] = (_Float16)b.y; r[6] = (_Float16)b.z; r[7] = (_Float16)b.w;
    return r;
}

// ---------------- Kernel 1: fused cvt + projections via MFMA (R4 verbatim) --
// Wave w: 2 m-tiles at (w>>4)*32, h-tile (w&15)*16. Direct f32 global fragment
// loads, cvt in-register. D layout (m89): lane l, reg r -> row m0+(l>>4)*4+r,
// col h0+(l&15).
__global__ __launch_bounds__(256) void k1_mfma(
    const float* __restrict__ xa, const float* __restrict__ W1,
    const float* __restrict__ b1, const float* __restrict__ w2,
    _Float16* __restrict__ Ah, _Float16* __restrict__ CP8,
    _Float16* __restrict__ w2h)
{
    const int t  = threadIdx.x;
    const int w  = blockIdx.x * 4 + (t >> 6);   // 0..1023
    const int l  = t & 63;
    const int mg = w >> 4;                      // 0..63
    const int h0 = (w & 15) * 16;
    const int lm = l & 15;
    const int lk = (l >> 4) * 8;
    const int m0 = mg * 32;

    h8 af[2][4];
    const float* xp0 = xa + (size_t)(m0 + lm) * F + lk;
    const float* xp1 = xp0 + 16 * F;
    #pragma unroll
    for (int kk = 0; kk < 4; ++kk) {
        af[0][kk] = cvt8(*(const float4*)(xp0 + kk * 32),
                         *(const float4*)(xp0 + kk * 32 + 4));
        af[1][kk] = cvt8(*(const float4*)(xp1 + kk * 32),
                         *(const float4*)(xp1 + kk * 32 + 4));
    }

    const float* wp = W1 + (size_t)(h0 + lm) * F2 + lk;
    f4 accA0 = {0.f,0.f,0.f,0.f}, accA1 = {0.f,0.f,0.f,0.f};
    f4 accC0 = {0.f,0.f,0.f,0.f}, accC1 = {0.f,0.f,0.f,0.f};
    #pragma unroll
    for (int kk = 0; kk < 4; ++kk) {
        h8 ba = cvt8(*(const float4*)(wp + kk * 32),
                     *(const float4*)(wp + kk * 32 + 4));
        h8 bb = cvt8(*(const float4*)(wp + F + kk * 32),
                     *(const float4*)(wp + F + kk * 32 + 4));
        accA0 = __builtin_amdgcn_mfma_f32_16x16x32_f16(af[0][kk], ba, accA0, 0, 0, 0);
        accC0 = __builtin_amdgcn_mfma_f32_16x16x32_f16(af[0][kk], bb, accC0, 0, 0, 0);
        accA1 = __builtin_amdgcn_mfma_f32_16x16x32_f16(af[1][kk], ba, accA1, 0, 0, 0);
        accC1 = __builtin_amdgcn_mfma_f32_16x16x32_f16(af[1][kk], bb, accC1, 0, 0, 0);
    }

    const int h  = h0 + lm;
    const float bh = b1[h];
    #pragma unroll
    for (int mt = 0; mt < 2; ++mt) {
        const f4 aA = mt ? accA1 : accA0;
        const f4 aC = mt ? accC1 : accC0;
        const int mb = m0 + mt * 16 + (l >> 4) * 4;
        #pragma unroll
        for (int r = 0; r < 4; ++r) {
            const int m = mb + r;
            Ah[(size_t)m * H + h] = (_Float16)(aA[r] + bh);
            // h-octet-packed Cc: CP8[((b*HOCT+h/8)*C + i)*8 + (h&7)]
            CP8[(((size_t)((m >> 8) * HOCT + (h >> 3)) * C + (m & 255)) << 3) + (h & 7)]
                = (_Float16)aC[r];
        }
    }

    if (blockIdx.x == 0 && t < 128) {   // w2 -> fp16 once
        float2 wv = ((const float2*)w2)[t];
        h2 hv = {(_Float16)wv.x, (_Float16)wv.y};
        ((h2*)w2h)[t] = hv;
    }
}

// ---------------- Kernel 2: pairwise relu + MFMA-matvec + sigmoid ----------
// Grid 512 = b(8) x it(32) x jh(2); 512 threads = 8 waves, wave owns a j-16-tile.
// Per wave: 16j x 8i x 256h. S-frag: lane l holds S[j0+(l&15)][32s+(l>>4)*8+:8]
// = relu(a + cc) in fp16 -> MFMA A operand. B operand = w2 replicated over n
// (lane value w2[k-slice], independent of l&15) -> D[j][n] = sum_k S[j,k]w2[k].
// D layout: lane l reg r -> j = j0 + (l>>4)*4 + r (cols all equal).
__global__ __launch_bounds__(512) void k2_mm(
    const _Float16* __restrict__ Ah, const _Float16* __restrict__ CP8,
    const _Float16* __restrict__ w2h, const float* __restrict__ b2p,
    float* __restrict__ out)
{
    const int t    = threadIdx.x;
    const int blk  = blockIdx.x;            // b*64 + it*2 + jh
    const int jh   = blk & 1;
    const int it   = (blk >> 1) & 31;
    const int b    = blk >> 6;
    const int i0   = it * 8;
    const int w    = t >> 6;                 // 0..7
    const int l    = t & 63;
    const int jrow = l & 15;
    const int ks   = l >> 4;                 // 0..3 (k-slice / h-octet group)
    const int j0   = (jh * 8 + w) * 16;
    const int j    = j0 + jrow;

    // Hoist cc- and w2-fragments for all 8 K-steps (reused across 8 i's).
    h8 ccf[8], w2f[8];
    #pragma unroll
    for (int s = 0; s < 8; ++s) {
        const int hoct = 4 * s + ks;
        ccf[s] = *(const h8*)(CP8 + (((size_t)(b * HOCT + hoct) * C + j) << 3));
        w2f[s] = *(const h8*)(w2h + hoct * 8);
    }

    f4 acc[8];
    #pragma unroll
    for (int i = 0; i < 8; ++i) acc[i] = (f4){0.f, 0.f, 0.f, 0.f};

    const _Float16* Ab = Ah + (size_t)(b * C + i0) * H + ks * 8;
    const h8 z = {0, 0, 0, 0, 0, 0, 0, 0};
    #pragma unroll
    for (int s = 0; s < 8; ++s) {
        #pragma unroll
        for (int i = 0; i < 8; ++i) {
            h8 ao = *(const h8*)(Ab + (size_t)i * H + s * 32);  // L1 broadcast
            h8 sum = ao + ccf[s];                                // v_pk_add_f16
            sum = __builtin_elementwise_max(sum, z);             // v_pk_max_f16
            acc[i] = __builtin_amdgcn_mfma_f32_16x16x32_f16(sum, w2f[s], acc[i], 0, 0, 0);
        }
    }

    // Epilogue: lanes with jrow==0 hold 4 j's each (regs r) per i.
    if (jrow == 0) {
        const float bb = b2p[0];
        #pragma unroll
        for (int i = 0; i < 8; ++i) {
            float4 o;
            o.x = 1.f / (1.f + __expf(-(acc[i][0] + bb)));
            o.y = 1.f / (1.f + __expf(-(acc[i][1] + bb)));
            o.z = 1.f / (1.f + __expf(-(acc[i][2] + bb)));
            o.w = 1.f / (1.f + __expf(-(acc[i][3] + bb)));
            *(float4*)(out + ((size_t)(b * C + i0 + i) * C + j0 + ks * 4)) = o;
        }
    }
}

extern "C" void kernel_launch(void* const* d_in, const int* in_sizes, int n_in,
                              void* d_out, int out_size, void* d_ws, size_t ws_size,
                              hipStream_t stream) {
    const float* xa = (const float*)d_in[0];
    const float* W1 = (const float*)d_in[1];
    const float* b1 = (const float*)d_in[2];
    const float* w2 = (const float*)d_in[3];
    const float* b2 = (const float*)d_in[4];
    float* out = (float*)d_out;

    _Float16* Ah  = (_Float16*)d_ws;                  // 1 MB
    _Float16* CP8 = Ah  + (size_t)B * C * H;          // 1 MB
    _Float16* w2h = CP8 + (size_t)B * H * C;          // 512 B

    k1_mfma<<<256, 256, 0, stream>>>(xa, W1, b1, w2, Ah, CP8, w2h);
    k2_mm<<<512, 512, 0, stream>>>(Ah, CP8, w2h, b2, out);
}

// Round 7
// 26.687 us; speedup vs baseline: 2.3365x; 1.1369x over previous
//
#include <hip/hip_runtime.h>

// EdgeSelectionRL: out[b,i,j] = sigmoid( sum_h relu(A[b,i,h] + Cc[b,j,h]) * w2[h] + b2 )
// A = xa·Wa^T + b1, Cc = xa·Wb^T.  B=8, C=256, F=128, H=256.
// R7: k1 = R4 verbatim. k2 = MFMA-matvec (R6 algorithm) with bounded live
// window: s-loop unroll 2, per-slice cc/w2 loads (R6's full unroll hoisted
// ~64 loads + 96 VGPR of fragments -> spill -> +6.5us scratch traffic).
// Model: 15.1us base + 2.1/node + work (k1 ~0.7, k2 ~2.1).

typedef _Float16 h2 __attribute__((ext_vector_type(2)));
typedef _Float16 h8 __attribute__((ext_vector_type(8)));
typedef float    f4 __attribute__((ext_vector_type(4)));

constexpr int B  = 8;
constexpr int C  = 256;
constexpr int F  = 128;
constexpr int H  = 256;
constexpr int F2 = 2 * F;     // 256
constexpr int HOCT = H / 8;   // 32

__device__ __forceinline__ h8 cvt8(float4 a, float4 b) {
    h8 r;
    r[0] = (_Float16)a.x; r[1] = (_Float16)a.y; r[2] = (_Float16)a.z; r[3] = (_Float16)a.w;
    r[4] = (_Float16)b.x; r[5] = (_Float16)b.y; r[6] = (_Float16)b.z; r[7] = (_Float16)b.w;
    return r;
}

// ---------------- Kernel 1: fused cvt + projections via MFMA (R4 verbatim) --
// Wave w: 2 m-tiles at (w>>4)*32, h-tile (w&15)*16. Direct f32 global fragment
// loads, cvt in-register. D layout (m89): lane l, reg r -> row m0+(l>>4)*4+r,
// col h0+(l&15).
__global__ __launch_bounds__(256) void k1_mfma(
    const float* __restrict__ xa, const float* __restrict__ W1,
    const float* __restrict__ b1, const float* __restrict__ w2,
    _Float16* __restrict__ Ah, _Float16* __restrict__ CP8,
    _Float16* __restrict__ w2h)
{
    const int t  = threadIdx.x;
    const int w  = blockIdx.x * 4 + (t >> 6);   // 0..1023
    const int l  = t & 63;
    const int mg = w >> 4;                      // 0..63
    const int h0 = (w & 15) * 16;
    const int lm = l & 15;
    const int lk = (l >> 4) * 8;
    const int m0 = mg * 32;

    h8 af[2][4];
    const float* xp0 = xa + (size_t)(m0 + lm) * F + lk;
    const float* xp1 = xp0 + 16 * F;
    #pragma unroll
    for (int kk = 0; kk < 4; ++kk) {
        af[0][kk] = cvt8(*(const float4*)(xp0 + kk * 32),
                         *(const float4*)(xp0 + kk * 32 + 4));
        af[1][kk] = cvt8(*(const float4*)(xp1 + kk * 32),
                         *(const float4*)(xp1 + kk * 32 + 4));
    }

    const float* wp = W1 + (size_t)(h0 + lm) * F2 + lk;
    f4 accA0 = {0.f,0.f,0.f,0.f}, accA1 = {0.f,0.f,0.f,0.f};
    f4 accC0 = {0.f,0.f,0.f,0.f}, accC1 = {0.f,0.f,0.f,0.f};
    #pragma unroll
    for (int kk = 0; kk < 4; ++kk) {
        h8 ba = cvt8(*(const float4*)(wp + kk * 32),
                     *(const float4*)(wp + kk * 32 + 4));
        h8 bb = cvt8(*(const float4*)(wp + F + kk * 32),
                     *(const float4*)(wp + F + kk * 32 + 4));
        accA0 = __builtin_amdgcn_mfma_f32_16x16x32_f16(af[0][kk], ba, accA0, 0, 0, 0);
        accC0 = __builtin_amdgcn_mfma_f32_16x16x32_f16(af[0][kk], bb, accC0, 0, 0, 0);
        accA1 = __builtin_amdgcn_mfma_f32_16x16x32_f16(af[1][kk], ba, accA1, 0, 0, 0);
        accC1 = __builtin_amdgcn_mfma_f32_16x16x32_f16(af[1][kk], bb, accC1, 0, 0, 0);
    }

    const int h  = h0 + lm;
    const float bh = b1[h];
    #pragma unroll
    for (int mt = 0; mt < 2; ++mt) {
        const f4 aA = mt ? accA1 : accA0;
        const f4 aC = mt ? accC1 : accC0;
        const int mb = m0 + mt * 16 + (l >> 4) * 4;
        #pragma unroll
        for (int r = 0; r < 4; ++r) {
            const int m = mb + r;
            Ah[(size_t)m * H + h] = (_Float16)(aA[r] + bh);
            // h-octet-packed Cc: CP8[((b*HOCT+h/8)*C + i)*8 + (h&7)]
            CP8[(((size_t)((m >> 8) * HOCT + (h >> 3)) * C + (m & 255)) << 3) + (h & 7)]
                = (_Float16)aC[r];
        }
    }

    if (blockIdx.x == 0 && t < 128) {   // w2 -> fp16 once
        float2 wv = ((const float2*)w2)[t];
        h2 hv = {(_Float16)wv.x, (_Float16)wv.y};
        ((h2*)w2h)[t] = hv;
    }
}

// ---------------- Kernel 2: pairwise relu + MFMA-matvec + sigmoid ----------
// Grid 512 = b(8) x it(32) x jh(2); 512 threads = 8 waves, wave owns a j-16-tile
// x 8 i-rows x 256 h. S-frag: lane l holds S[j0+(l&15)][32s+(l>>4)*8 +: 8]
// = relu(a + cc) fp16 -> MFMA A operand. B operand = w2 replicated over n
// -> D[j][n] = sum_k S[j,k]w2[k] (all n equal). s-loop unroll 2 bounds the
// live-register window (R6's full unroll spilled).
__global__ __launch_bounds__(512) void k2_mm(
    const _Float16* __restrict__ Ah, const _Float16* __restrict__ CP8,
    const _Float16* __restrict__ w2h, const float* __restrict__ b2p,
    float* __restrict__ out)
{
    const int t    = threadIdx.x;
    const int blk  = blockIdx.x;            // b*64 + it*2 + jh
    const int jh   = blk & 1;
    const int it   = (blk >> 1) & 31;
    const int b    = blk >> 6;
    const int i0   = it * 8;
    const int w    = t >> 6;                 // 0..7
    const int l    = t & 63;
    const int jrow = l & 15;
    const int ks   = l >> 4;                 // 0..3 (k-slice / h-octet in group)
    const int j0   = (jh * 8 + w) * 16;
    const int j    = j0 + jrow;

    f4 acc[8];
    #pragma unroll
    for (int i = 0; i < 8; ++i) acc[i] = (f4){0.f, 0.f, 0.f, 0.f};

    const _Float16* Ab  = Ah + (size_t)(b * C + i0) * H + ks * 8;
    const _Float16* CPb = CP8 + (((size_t)(b * HOCT + ks) * C + j) << 3);
    const h8 z = {0, 0, 0, 0, 0, 0, 0, 0};

    #pragma unroll 2
    for (int s = 0; s < 8; ++s) {
        // octet index hoct = 4s + ks; k-window = h in [32s, 32s+32)
        h8 cc = *(const h8*)(CPb + ((size_t)(4 * s) * C << 3));
        h8 wv = *(const h8*)(w2h + (4 * s + ks) * 8);
        #pragma unroll
        for (int i = 0; i < 8; ++i) {
            h8 ao  = *(const h8*)(Ab + (size_t)i * H + s * 32); // L1 broadcast
            h8 sum = __builtin_elementwise_max(ao + cc, z);     // pk_add+pk_max
            acc[i] = __builtin_amdgcn_mfma_f32_16x16x32_f16(sum, wv, acc[i], 0, 0, 0);
        }
    }

    // Epilogue: lanes with jrow==0 hold 4 j's (regs r) per i, all n-cols equal.
    if (jrow == 0) {
        const float bb = b2p[0];
        #pragma unroll
        for (int i = 0; i < 8; ++i) {
            float4 o;
            o.x = 1.f / (1.f + __expf(-(acc[i][0] + bb)));
            o.y = 1.f / (1.f + __expf(-(acc[i][1] + bb)));
            o.z = 1.f / (1.f + __expf(-(acc[i][2] + bb)));
            o.w = 1.f / (1.f + __expf(-(acc[i][3] + bb)));
            *(float4*)(out + ((size_t)(b * C + i0 + i) * C + j0 + ks * 4)) = o;
        }
    }
}

extern "C" void kernel_launch(void* const* d_in, const int* in_sizes, int n_in,
                              void* d_out, int out_size, void* d_ws, size_t ws_size,
                              hipStream_t stream) {
    const float* xa = (const float*)d_in[0];
    const float* W1 = (const float*)d_in[1];
    const float* b1 = (const float*)d_in[2];
    const float* w2 = (const float*)d_in[3];
    const float* b2 = (const float*)d_in[4];
    float* out = (float*)d_out;

    _Float16* Ah  = (_Float16*)d_ws;                  // 1 MB
    _Float16* CP8 = Ah  + (size_t)B * C * H;          // 1 MB
    _Float16* w2h = CP8 + (size_t)B * H * C;          // 512 B

    k1_mfma<<<256, 256, 0, stream>>>(xa, W1, b1, w2, Ah, CP8, w2h);
    k2_mm<<<512, 512, 0, stream>>>(Ah, CP8, w2h, b2, out);
}